// Round 3
// baseline (50.497 us; speedup 1.0000x reference)
//
#include <hip/hip_runtime.h>

// CR gate, D=2, L=24, control=axis0, target=axis1.
// N = 2^24 amplitudes. Output = [N reals][N imags] of U @ x.
//
// control=0 half (first N/2 amplitudes): identity copy.
// control=1 half: M1 = cos(a/2) I - i sin(a/2) X across the target axis:
//   t=0 slice at f4-offset 2*2^20, t=1 slice at 3*2^20 (per array).
//
// Structure: block-region split with compile-time unroll so all loads issue
// before all stores (max outstanding VMEM per wave).
//   blocks [0, 2048):    copy,   4 f32x4 units/thread (xr+xi)
//   blocks [2048, 4096): rotate, 2 f32x4 pair-units/thread

#define NELEM   (1u << 24)
#define R4      (1u << 20)            // R/4 in f32x4 units
#define CPY_BLOCKS 2048u
#define ROT_BLOCKS 2048u
#define CPY_STRIDE (CPY_BLOCKS * 256u)   // 2^19: copy units per sweep
#define ROT_STRIDE (ROT_BLOCKS * 256u)   // 2^19: rotate units per sweep

typedef float f32x4 __attribute__((ext_vector_type(4)));

__global__ __launch_bounds__(256, 8) void cr_gate_kernel(
    const f32x4* __restrict__ xr,
    const f32x4* __restrict__ xi,
    const float* __restrict__ angle,
    f32x4* __restrict__ outr,
    f32x4* __restrict__ outi)
{
    const unsigned bid = blockIdx.x;
    const unsigned tid = threadIdx.x;

    if (bid < CPY_BLOCKS) {
        // ---- control = 0: identity copy of f4 indices [0, 2^21) ----
        const unsigned base = bid * 256u + tid;
        f32x4 a[4], b[4];
        #pragma unroll
        for (int k = 0; k < 4; ++k) {
            a[k] = xr[base + (unsigned)k * CPY_STRIDE];
            b[k] = xi[base + (unsigned)k * CPY_STRIDE];
        }
        #pragma unroll
        for (int k = 0; k < 4; ++k) {
            __builtin_nontemporal_store(a[k], &outr[base + (unsigned)k * CPY_STRIDE]);
            __builtin_nontemporal_store(b[k], &outi[base + (unsigned)k * CPY_STRIDE]);
        }
    } else {
        // ---- control = 1: rotate target pairs, j in [0, 2^20) ----
        const float half_a = 0.5f * angle[0];
        float s, c;
        sincosf(half_a, &s, &c);

        const unsigned base = (bid - CPY_BLOCKS) * 256u + tid;
        f32x4 r0[2], i0[2], r1[2], i1[2];
        #pragma unroll
        for (int k = 0; k < 2; ++k) {
            const unsigned j  = base + (unsigned)k * ROT_STRIDE;
            const unsigned ia = 2u * R4 + j;
            const unsigned ib = 3u * R4 + j;
            r0[k] = xr[ia];
            i0[k] = xi[ia];
            r1[k] = xr[ib];
            i1[k] = xi[ib];
        }
        #pragma unroll
        for (int k = 0; k < 2; ++k) {
            const unsigned j  = base + (unsigned)k * ROT_STRIDE;
            const unsigned ia = 2u * R4 + j;
            const unsigned ib = 3u * R4 + j;
            // out0 = c*x0 - i s*x1 ; out1 = -i s*x0 + c*x1
            f32x4 or0 = c * r0[k] + s * i1[k];
            f32x4 oi0 = c * i0[k] - s * r1[k];
            f32x4 or1 = c * r1[k] + s * i0[k];
            f32x4 oi1 = c * i1[k] - s * r0[k];
            __builtin_nontemporal_store(or0, &outr[ia]);
            __builtin_nontemporal_store(oi0, &outi[ia]);
            __builtin_nontemporal_store(or1, &outr[ib]);
            __builtin_nontemporal_store(oi1, &outi[ib]);
        }
    }
}

extern "C" void kernel_launch(void* const* d_in, const int* in_sizes, int n_in,
                              void* d_out, int out_size, void* d_ws, size_t ws_size,
                              hipStream_t stream)
{
    const f32x4* xr    = (const f32x4*)d_in[0];
    const f32x4* xi    = (const f32x4*)d_in[1];
    const float* angle = (const float*)d_in[2];

    float* out  = (float*)d_out;
    f32x4* outr = (f32x4*)out;            // first N floats: real part
    f32x4* outi = (f32x4*)(out + NELEM);  // next  N floats: imag part

    cr_gate_kernel<<<CPY_BLOCKS + ROT_BLOCKS, 256, 0, stream>>>(xr, xi, angle, outr, outi);
}

// Round 4
// 45.628 us; speedup vs baseline: 1.1067x; 1.1067x over previous
//
#include <hip/hip_runtime.h>

// CR gate, D=2, L=24, control=axis0, target=axis1.
// N = 2^24 amplitudes. Output = [N reals][N imags] of U @ x.
//
// control=0 half (first N/2 amplitudes of each array): identity copy.
// control=1 half: M1 = cos(a/2) I - i sin(a/2) X across the target axis:
//   t=0 slice at f4-offset 2^21, t=1 slice at 3*2^20 (per array).
//
// Fully static work assignment: grid = 4096 blocks * 256 threads = 2^20
// threads; thread b handles copy units {b, b + 2^20} and rotate pair b.
// Per thread: 8 f32x4 loads (all issued first), then 8 f32x4 stores.
// Every wave carries both copy and rotate traffic (the round-3 block-
// specialized variant regressed; homogeneous per-wave mix is faster).

#define NELEM (1u << 24)
#define Q4    (1u << 20)   // 2^20 f32x4 units = one quarter of each array

typedef float f32x4 __attribute__((ext_vector_type(4)));

__global__ __launch_bounds__(256) void cr_gate_kernel(
    const f32x4* __restrict__ xr,
    const f32x4* __restrict__ xi,
    const float* __restrict__ angle,
    f32x4* __restrict__ outr,
    f32x4* __restrict__ outi)
{
    const unsigned b = blockIdx.x * 256u + threadIdx.x;   // [0, 2^20)

    const float half_a = 0.5f * angle[0];
    float s, c;
    sincosf(half_a, &s, &c);

    // ---- issue all 8 loads ----
    // copy units (control = 0): quarters 0 and 1
    f32x4 c0r = xr[b];
    f32x4 c0i = xi[b];
    f32x4 c1r = xr[b + Q4];
    f32x4 c1i = xi[b + Q4];
    // rotate pair (control = 1): t=0 at quarter 2, t=1 at quarter 3
    f32x4 r0 = xr[b + 2u * Q4];
    f32x4 i0 = xi[b + 2u * Q4];
    f32x4 r1 = xr[b + 3u * Q4];
    f32x4 i1 = xi[b + 3u * Q4];

    // ---- compute rotate: out0 = c*x0 - i s*x1 ; out1 = -i s*x0 + c*x1 ----
    f32x4 or0 = c * r0 + s * i1;
    f32x4 oi0 = c * i0 - s * r1;
    f32x4 or1 = c * r1 + s * i0;
    f32x4 oi1 = c * i1 - s * r0;

    // ---- stores ----
    __builtin_nontemporal_store(c0r, &outr[b]);
    __builtin_nontemporal_store(c0i, &outi[b]);
    __builtin_nontemporal_store(c1r, &outr[b + Q4]);
    __builtin_nontemporal_store(c1i, &outi[b + Q4]);
    __builtin_nontemporal_store(or0, &outr[b + 2u * Q4]);
    __builtin_nontemporal_store(oi0, &outi[b + 2u * Q4]);
    __builtin_nontemporal_store(or1, &outr[b + 3u * Q4]);
    __builtin_nontemporal_store(oi1, &outi[b + 3u * Q4]);
}

extern "C" void kernel_launch(void* const* d_in, const int* in_sizes, int n_in,
                              void* d_out, int out_size, void* d_ws, size_t ws_size,
                              hipStream_t stream)
{
    const f32x4* xr    = (const f32x4*)d_in[0];
    const f32x4* xi    = (const f32x4*)d_in[1];
    const float* angle = (const float*)d_in[2];

    float* out  = (float*)d_out;
    f32x4* outr = (f32x4*)out;            // first N floats: real part
    f32x4* outi = (f32x4*)(out + NELEM);  // next  N floats: imag part

    cr_gate_kernel<<<4096, 256, 0, stream>>>(xr, xi, angle, outr, outi);
}